// Round 5
// baseline (3741.400 us; speedup 1.0000x reference)
//
#include <hip/hip_runtime.h>
#include <cstdint>
#include <cstddef>
#include <type_traits>

#define T_STEPS 16
#define BB 512
#define NF 1024
#define NI 256
#define NH 2048
#define KSTEPS 5

typedef __bf16 bf16;
typedef __bf16 bf16x8 __attribute__((ext_vector_type(8)));
typedef __bf16 bf16x4 __attribute__((ext_vector_type(4)));
typedef float f32x4 __attribute__((ext_vector_type(4)));

enum { EPI_BF16 = 0, EPI_F32 = 1, EPI_TEMPS = 2, EPI_W1 = 3 };

__device__ __forceinline__ void gload_lds16(const bf16* g, void* l) {
  __builtin_amdgcn_global_load_lds(
      (const __attribute__((address_space(1))) void*)g,
      (__attribute__((address_space(3))) void*)l, 16, 0, 0);
}

// faithful multi-branch prox of w0*|x| + w1*|x - a1|
__device__ __forceinline__ float soft_l1_l1(float z, float w0, float w1, float a1) {
  bool c = (0.0f <= a1);
  float a0s = c ? 0.0f : a1;
  float a1s = c ? a1 : 0.0f;
  float w0s = c ? w0 : w1;
  float w1s = c ? w1 : w0;
  if (z >= a1s + w0s + w1s) return z - w0s - w1s;
  if (z >= a1s + w0s - w1s) return a1s;
  if (z >= a0s + w0s - w1s) return z - w0s + w1s;
  if (z >= a0s - w0s - w1s) return a0s;
  return z + w0s + w1s;
}

// ---------------------------------------------------------------------------
// Batched GEMM: C[m,n] = sum_k Ag[m,k]*Bg[n,k].  128x128 tile, BK=64,
// 4 waves (2x2) each owning a 64x64 sub-tile.  D=2 buffers (64KB LDS ->
// 2 blocks/CU), counted vmcnt(8) + raw barriers.  1-D grid, XCD chunking
// (bid&7 -> contiguous wg range), COL-FASTEST decode so each XCD chunk is a
// row-band x all col-tiles (A-slice + full B stream per XCD, not full A).
// ---------------------------------------------------------------------------
template<int EPI>
__global__ __launch_bounds__(256)
void gemm_bt2(const bf16* __restrict__ Ag, const bf16* __restrict__ Bg,
              int N, int Kd, int nby, int total,
              bf16* __restrict__ outb, float* __restrict__ outf,
              bf16* __restrict__ out2, const float* __restrict__ srcf,
              const float* __restrict__ alpha, int inv_alpha)
{
  __shared__ char smem[65536];   // 2 bufs x (A 16KB + B 16KB)
  const int tid = threadIdx.x, lane = tid & 63, wid = tid >> 6;
  const int wr = wid >> 1, wc = wid & 1;
  const int r16 = lane & 15, q16 = lane >> 4;
  const int bid = blockIdx.x;
  const int wg = (bid & 7) * (total >> 3) + (bid >> 3);
  const int bm0 = (wg / nby) * 128, bn0 = (wg % nby) * 128;
  const int sw = r16 & 7;

  f32x4 acc[4][4] = {};

  auto stage = [&](int buf, int kt) {
    char* da = smem + buf * 32768;
    char* db = da + 16384;
#pragma unroll
    for (int it = 0; it < 4; ++it) {
      int idx = it * 256 + tid;
      int row = idx >> 3, sc = (idx & 7) ^ (row & 7);
      gload_lds16(Ag + (size_t)(bm0 + row) * Kd + kt + sc * 8, da + idx * 16);
    }
#pragma unroll
    for (int it = 0; it < 4; ++it) {
      int idx = it * 256 + tid;
      int row = idx >> 3, sc = (idx & 7) ^ (row & 7);
      gload_lds16(Bg + (size_t)(bn0 + row) * Kd + kt + sc * 8, db + idx * 16);
    }
  };

  auto compute = [&](int buf) {
    const char* Ab = smem + buf * 32768;
    const char* Bb = Ab + 16384;
#pragma unroll
    for (int kk = 0; kk < 2; ++kk) {
      int ch = ((kk * 4 + q16) ^ sw) * 16;
      bf16x8 af[4], bfr[4];
#pragma unroll
      for (int i = 0; i < 4; ++i)
        af[i] = *(const bf16x8*)(Ab + (wr * 64 + i * 16 + r16) * 128 + ch);
#pragma unroll
      for (int j = 0; j < 4; ++j)
        bfr[j] = *(const bf16x8*)(Bb + (wc * 64 + j * 16 + r16) * 128 + ch);
#pragma unroll
      for (int i = 0; i < 4; ++i)
#pragma unroll
        for (int j = 0; j < 4; ++j)
          acc[i][j] = __builtin_amdgcn_mfma_f32_16x16x32_bf16(af[i], bfr[j], acc[i][j], 0, 0, 0);
    }
  };

  const int NT = Kd >> 6;
  stage(0, 0);
  int t = 0;
  for (; t < NT - 1; ++t) {
    stage((t + 1) & 1, (t + 1) * 64);
    asm volatile("s_waitcnt vmcnt(8)" ::: "memory");
    __builtin_amdgcn_s_barrier();
    __builtin_amdgcn_sched_barrier(0);
    compute(t & 1);
    __builtin_amdgcn_sched_barrier(0);
    __builtin_amdgcn_s_barrier();
  }
  asm volatile("s_waitcnt vmcnt(0)" ::: "memory");
  __builtin_amdgcn_s_barrier();
  __builtin_amdgcn_sched_barrier(0);
  compute(t & 1);

  float scale = inv_alpha ? 1.f / alpha[0] : 1.f;
#pragma unroll
  for (int i = 0; i < 4; ++i) {
#pragma unroll
    for (int j = 0; j < 4; ++j) {
#pragma unroll
      for (int e = 0; e < 4; ++e) {
        int m = bm0 + wr * 64 + i * 16 + q16 * 4 + e;
        int n = bn0 + wc * 64 + j * 16 + r16;
        size_t o = (size_t)m * N + n;
        float v = acc[i][j][e] * scale;
        if (EPI == EPI_BF16) {
          outb[o] = (bf16)v;
        } else if (EPI == EPI_F32) {
          outf[o] = v;
        } else if (EPI == EPI_TEMPS) {
          outb[o] = (bf16)v;
          out2[o] = (bf16)((m == n ? 1.f : 0.f) - v);
        } else { // EPI_W1
          outb[o] = (bf16)(srcf[o] - v);
        }
      }
    }
  }
}

// ---------------------------------------------------------------------------
// Persistent scan: ONE kernel runs all T_STEPS*KSTEPS = 80 GEMM phases with a
// software grid barrier between phases. grid = 256 blocks (1/CU, provably
// co-resident: 256 blocks, 144KB LDS, <=256 VGPR), 256 threads.
// Block (bid) owns output tile: xcd=bid&7 pins a 256-col slice of S/W1/G in
// that XCD's L2 for the WHOLE scan; bm0/bn0 as before. Per phase: 64x64
// output over K=2048, BK=128, wave-level K-split + LDS cross-wave reduce.
// xv tile and a1 tile live in REGISTERS across the 5 k-iterations.
// Cross-XCD h visibility: release atomicAdd (L2 writeback) + acquire spin +
// __threadfence (invalidate) at each barrier.
// ---------------------------------------------------------------------------
template<bool DUAL>
__device__ __forceinline__ void phase_gemm(
    char* smem, const bf16* __restrict__ Ag, const bf16* __restrict__ B1g,
    const bf16* __restrict__ B2g, int bm0, int bn0, int tid, int chbase,
    f32x4 (&sz)[4], f32x4 (&sg)[4])
{
  const int lane = tid & 63, wid = tid >> 6;
  const int r16 = lane & 15;
  constexpr int Kd = NH;
  constexpr int HALF = 49152;   // A@0 + B1@16K + B2@32K per buffer, 3 buffers

  f32x4 accW[4][4] = {};
  f32x4 accG[4][4] = {};   // DCE'd when !DUAL

  auto stage = [&](int buf, int kt) {
    char* base = smem + buf * HALF;
#pragma unroll
    for (int it = 0; it < 4; ++it) {
      int idx = it * 256 + tid;
      int row = idx >> 4, sc = (idx & 15) ^ (row & 7);
      gload_lds16(Ag + (size_t)(bm0 + row) * Kd + kt + sc * 8, base + idx * 16);
    }
#pragma unroll
    for (int it = 0; it < 4; ++it) {
      int idx = it * 256 + tid;
      int row = idx >> 4, sc = (idx & 15) ^ (row & 7);
      gload_lds16(B1g + (size_t)(bn0 + row) * Kd + kt + sc * 8, base + 16384 + idx * 16);
    }
    if constexpr (DUAL) {
#pragma unroll
      for (int it = 0; it < 4; ++it) {
        int idx = it * 256 + tid;
        int row = idx >> 4, sc = (idx & 15) ^ (row & 7);
        gload_lds16(B2g + (size_t)(bn0 + row) * Kd + kt + sc * 8, base + 32768 + idx * 16);
      }
    }
  };

  auto compute = [&](int buf) {
    const char* Ab = smem + buf * HALF;
    const char* B1b = Ab + 16384;
    bf16x8 af[4], b1[4];
#pragma unroll
    for (int i = 0; i < 4; ++i)
      af[i] = *(const bf16x8*)(Ab + (i * 16 + r16) * 256 + chbase);
#pragma unroll
    for (int j = 0; j < 4; ++j)
      b1[j] = *(const bf16x8*)(B1b + (j * 16 + r16) * 256 + chbase);
#pragma unroll
    for (int i = 0; i < 4; ++i)
#pragma unroll
      for (int j = 0; j < 4; ++j)
        accW[i][j] = __builtin_amdgcn_mfma_f32_16x16x32_bf16(af[i], b1[j], accW[i][j], 0, 0, 0);
    if constexpr (DUAL) {
      const char* B2b = Ab + 32768;
      bf16x8 b2[4];
#pragma unroll
      for (int j = 0; j < 4; ++j)
        b2[j] = *(const bf16x8*)(B2b + (j * 16 + r16) * 256 + chbase);
#pragma unroll
      for (int i = 0; i < 4; ++i)
#pragma unroll
        for (int j = 0; j < 4; ++j)
          accG[i][j] = __builtin_amdgcn_mfma_f32_16x16x32_bf16(af[i], b2[j], accG[i][j], 0, 0, 0);
    }
  };

  constexpr int NT = 16;
  stage(0, 0);
  stage(1, 128);
  int sb = 2, cb = 0;
  for (int tt = 0; tt < NT; ++tt) {
    if (tt < NT - 2) {
      stage(sb, (tt + 2) * 128);
      sb = (sb + 1 == 3) ? 0 : sb + 1;
      if constexpr (DUAL) asm volatile("s_waitcnt vmcnt(24)" ::: "memory");
      else                asm volatile("s_waitcnt vmcnt(16)" ::: "memory");
    } else if (tt == NT - 2) {
      if constexpr (DUAL) asm volatile("s_waitcnt vmcnt(12)" ::: "memory");
      else                asm volatile("s_waitcnt vmcnt(8)" ::: "memory");
    } else {
      asm volatile("s_waitcnt vmcnt(0)" ::: "memory");
    }
    __builtin_amdgcn_s_barrier();
    __builtin_amdgcn_sched_barrier(0);
    compute(cb);
    cb = (cb + 1 == 3) ? 0 : cb + 1;
    __builtin_amdgcn_sched_barrier(0);
    __builtin_amdgcn_s_barrier();
  }
  __syncthreads();

  // cross-wave K-reduce via LDS (aliases staging; all loads drained above)
  float* red = (float*)smem;
  const int myrow = tid * 76;
  const int lrow = lane * 76;
  if constexpr (DUAL) {
#pragma unroll
    for (int i = 0; i < 4; ++i)
#pragma unroll
      for (int j = 0; j < 4; ++j)
        *(f32x4*)&red[myrow + (i * 4 + j) * 4] = accG[i][j];
    __syncthreads();
#pragma unroll
    for (int j = 0; j < 4; ++j) {
      sg[j] = *(const f32x4*)&red[lrow + wid * 16 + j * 4];
#pragma unroll
      for (int w = 1; w < 4; ++w)
        sg[j] += *(const f32x4*)&red[w * 4864 + lrow + wid * 16 + j * 4];
    }
    __syncthreads();
  }
#pragma unroll
  for (int i = 0; i < 4; ++i)
#pragma unroll
    for (int j = 0; j < 4; ++j)
      *(f32x4*)&red[myrow + (i * 4 + j) * 4] = accW[i][j];
  __syncthreads();
#pragma unroll
  for (int j = 0; j < 4; ++j) {
    sz[j] = *(const f32x4*)&red[lrow + wid * 16 + j * 4];
#pragma unroll
    for (int w = 1; w < 4; ++w)
      sz[j] += *(const f32x4*)&red[w * 4864 + lrow + wid * 16 + j * 4];
  }
  __syncthreads();   // reduce area reused as staging next phase
}

__global__ __launch_bounds__(256, 1)
void scan_persist(const bf16* __restrict__ H0, const bf16* __restrict__ W1m,
                  const bf16* __restrict__ Sm, const bf16* __restrict__ Gt,
                  const bf16* __restrict__ XV, bf16* __restrict__ Hb0,
                  bf16* __restrict__ Hb1, bf16* __restrict__ HS,
                  const float* __restrict__ alpha, const float* __restrict__ lam0,
                  const float* __restrict__ lam1, unsigned* __restrict__ cnt)
{
  __shared__ char smem[147456];
  const int tid = threadIdx.x, lane = tid & 63, wid = tid >> 6;
  const int r16 = lane & 15, q16 = lane >> 4;
  const int bid = blockIdx.x;
  const int xcd = bid & 7, r = bid >> 3;
  const int bn0 = xcd * 256 + (r & 3) * 64;
  const int bm0 = (r >> 2) * 64;
  const int sw = r16 & 7;
  const int chbase = ((wid * 4 + q16) ^ sw) * 16;

  const float al = alpha[0];
  const float w0 = lam0[0] / al, w1 = lam1[0] / al;
  const size_t HBsz = (size_t)BB * NH;

  unsigned bar_no = 0;
  auto grid_bar = [&]() {
    __syncthreads();
    ++bar_no;
    if (tid == 0) {
      __hip_atomic_fetch_add(cnt, 1u, __ATOMIC_RELEASE, __HIP_MEMORY_SCOPE_AGENT);
      while (__hip_atomic_load(cnt, __ATOMIC_ACQUIRE, __HIP_MEMORY_SCOPE_AGENT) <
             bar_no * 256u)
        __builtin_amdgcn_s_sleep(2);
    }
    __syncthreads();
    __threadfence();   // acquire: invalidate stale L1/L2 lines before reading h
  };

  f32x4 sz[4], sg[4];
  float xvreg[16], a1reg[16];

  for (int t = 0; t < T_STEPS; ++t) {
    const bf16* xvt = XV + (size_t)t * HBsz;
#pragma unroll
    for (int j = 0; j < 4; ++j)
#pragma unroll
      for (int e = 0; e < 4; ++e)
        xvreg[j * 4 + e] =
            (float)xvt[(size_t)(bm0 + wid * 16 + q16 * 4 + e) * NH + bn0 + j * 16 + r16];

    auto write_h = [&](bf16* dst) {
#pragma unroll
      for (int j = 0; j < 4; ++j)
#pragma unroll
        for (int e = 0; e < 4; ++e) {
          float z = sz[j][e] + xvreg[j * 4 + e];
          dst[(size_t)(bm0 + wid * 16 + q16 * 4 + e) * NH + bn0 + j * 16 + r16] =
              (bf16)soft_l1_l1(z, w0, w1, a1reg[j * 4 + e]);
        }
    };

    // k = 0: h = shrink(h_prev@W1^T + xv), a1 = h_prev@G^T (kept in regs)
    const bf16* hp = (t == 0) ? H0 : HS + (size_t)(t - 1) * HBsz;
    phase_gemm<true>(smem, hp, W1m, Gt, bm0, bn0, tid, chbase, sz, sg);
#pragma unroll
    for (int j = 0; j < 4; ++j)
#pragma unroll
      for (int e = 0; e < 4; ++e) a1reg[j * 4 + e] = sg[j][e];
    write_h(Hb0);
    grid_bar();

    // k = 1..4: h = shrink(xv + h@S^T)
    for (int k = 1; k < KSTEPS; ++k) {
      const bf16* src = (k & 1) ? Hb0 : Hb1;
      bf16* dst = (k == KSTEPS - 1) ? HS + (size_t)t * HBsz : ((k & 1) ? Hb1 : Hb0);
      phase_gemm<false>(smem, src, Sm, nullptr, bm0, bn0, tid, chbase, sz, sg);
      write_h(dst);
      grid_bar();
    }
  }
}

__global__ void zero_u32(unsigned* p) { *p = 0; }

__global__ void cast_f32_bf16(const float* __restrict__ in, bf16* __restrict__ out, int n) {
  int i = (blockIdx.x * blockDim.x + threadIdx.x) * 4;
  if (i + 4 <= n) {
    float4 v = *(const float4*)&in[i];
    bf16x4 p;
    p[0] = (bf16)v.x; p[1] = (bf16)v.y; p[2] = (bf16)v.z; p[3] = (bf16)v.w;
    *(bf16x4*)&out[i] = p;
  } else {
    for (; i < n; ++i) out[i] = (bf16)in[i];
  }
}

// out[c,r] = (bf16) in[r,c];  in: [R,C] f32 row-major -> out: [C,R] bf16 row-major
__global__ void transpose_cast(const float* __restrict__ in, bf16* __restrict__ out, int R, int C) {
  __shared__ float tile[32][33];
  int bx = blockIdx.x * 32, by = blockIdx.y * 32;
  int tx = threadIdx.x, ty = threadIdx.y;
  for (int i = ty; i < 32; i += 8) {
    int r = by + i, c = bx + tx;
    if (r < R && c < C) tile[i][tx] = in[(size_t)r * C + c];
  }
  __syncthreads();
  for (int i = ty; i < 32; i += 8) {
    int r = bx + i, c = by + tx;
    if (r < C && c < R) out[(size_t)r * R + c] = (bf16)tile[tx][i];
  }
}

extern "C" void kernel_launch(void* const* d_in, const int* in_sizes, int n_in,
                              void* d_out, int out_size, void* d_ws, size_t ws_size,
                              hipStream_t stream) {
  // inputs: 0 pre_input (unused), 1 raw, 2 A, 3 D, 4 G, 5 h_0,
  //         6 alpha, 7 lambda0, 8 lambda1, 9 K (fixed = 5)
  const float* rawf = (const float*)d_in[1];
  const float* Af   = (const float*)d_in[2];
  const float* Df   = (const float*)d_in[3];
  const float* Gf   = (const float*)d_in[4];
  const float* h0f  = (const float*)d_in[5];
  const float* alp  = (const float*)d_in[6];
  const float* l0   = (const float*)d_in[7];
  const float* l1   = (const float*)d_in[8];
  float* outp = (float*)d_out;

  char* w = (char*)d_ws;
  auto allocb = [&](size_t bytes) { char* p = w; w += (bytes + 255) & ~(size_t)255; return p; };
  bf16* Abf  = (bf16*)allocb((size_t)NI * NF * 2);
  bf16* At   = (bf16*)allocb((size_t)NF * NI * 2);
  bf16* Dbf  = (bf16*)allocb((size_t)NF * NH * 2);
  bf16* Dt   = (bf16*)allocb((size_t)NH * NF * 2);
  bf16* Gt   = (bf16*)allocb((size_t)NH * NH * 2);
  bf16* rawb = (bf16*)allocb((size_t)T_STEPS * BB * NF * 2);
  bf16* AtA  = (bf16*)allocb((size_t)NF * NF * 2);
  bf16* Vm   = (bf16*)allocb((size_t)NH * NI * 2);
  bf16* M3t  = (bf16*)allocb((size_t)NH * NF * 2);
  bf16* tmpb = (bf16*)allocb((size_t)NH * NH * 2);
  bf16* Sm   = (bf16*)allocb((size_t)NH * NH * 2);
  bf16* W1m  = (bf16*)allocb((size_t)NH * NH * 2);
  bf16* X    = (bf16*)allocb((size_t)T_STEPS * BB * NI * 2);
  bf16* H0   = (bf16*)allocb((size_t)BB * NH * 2);
  bf16* Hb0  = (bf16*)allocb((size_t)BB * NH * 2);
  bf16* Hb1  = (bf16*)allocb((size_t)BB * NH * 2);
  bf16* HS   = (bf16*)allocb((size_t)T_STEPS * BB * NH * 2);
  unsigned* cnt = (unsigned*)allocb(256);
  // XV (T*B x NH bf16 = 32 MB) lives in d_out: fully written before use, dead
  // before the final projection overwrites d_out.
  bf16* XV   = (bf16*)d_out;

  zero_u32<<<1, 1, 0, stream>>>(cnt);

  auto cgrid = [](int n) { return dim3((unsigned)((n / 4 + 255) / 256)); };
  cast_f32_bf16<<<cgrid(NI * NF), 256, 0, stream>>>(Af, Abf, NI * NF);
  cast_f32_bf16<<<cgrid(NF * NH), 256, 0, stream>>>(Df, Dbf, NF * NH);
  cast_f32_bf16<<<cgrid(T_STEPS * BB * NF), 256, 0, stream>>>(rawf, rawb, T_STEPS * BB * NF);
  cast_f32_bf16<<<cgrid(BB * NH), 256, 0, stream>>>(h0f, H0, BB * NH);
  transpose_cast<<<dim3(NF / 32, NI / 32), dim3(32, 8), 0, stream>>>(Af, At, NI, NF);
  transpose_cast<<<dim3(NH / 32, NF / 32), dim3(32, 8), 0, stream>>>(Df, Dt, NF, NH);
  transpose_cast<<<dim3(NH / 32, NH / 32), dim3(32, 8), 0, stream>>>(Gf, Gt, NH, NH);

  auto launch_bt2 = [&](auto epi_tag, int Mrows, int Ncols, int Kd,
                        const bf16* Ap, const bf16* Bp,
                        bf16* ob, float* of, bf16* o2, const float* sf, int inva) {
    constexpr int EPIv = decltype(epi_tag)::value;
    int nbx = Mrows / 128, nby = Ncols / 128, total = nbx * nby;
    gemm_bt2<EPIv><<<dim3(total), 256, 0, stream>>>(
        Ap, Bp, Ncols, Kd, nby, total, ob, of, o2, sf, alp, inva);
  };

  // AtA[f1,f2] = sum_i A[i,f1]A[i,f2]
  launch_bt2(std::integral_constant<int, EPI_BF16>{}, NF, NF, NI, At, At,
             AtA, nullptr, nullptr, nullptr, 0);
  // V[h,i] = (1/al) sum_f D[f,h]A[i,f]
  launch_bt2(std::integral_constant<int, EPI_BF16>{}, NH, NI, NF, Dt, Abf,
             Vm, nullptr, nullptr, nullptr, 1);
  // M3t[h,f] = sum_f2 Dt[h,f2]AtA[f,f2] = (AtA@D)[f,h]  (AtA symmetric)
  launch_bt2(std::integral_constant<int, EPI_BF16>{}, NH, NF, NF, Dt, AtA,
             M3t, nullptr, nullptr, nullptr, 0);
  // temp = (1/al) D^T (AtA D); S = I - temp (dual store)
  launch_bt2(std::integral_constant<int, EPI_TEMPS>{}, NH, NH, NF, Dt, M3t,
             tmpb, nullptr, Sm, nullptr, 1);
  // W1 = G - temp@G
  launch_bt2(std::integral_constant<int, EPI_W1>{}, NH, NH, NH, tmpb, Gt,
             W1m, nullptr, nullptr, Gf, 0);
  // X = raw @ A^T
  launch_bt2(std::integral_constant<int, EPI_BF16>{}, T_STEPS * BB, NI, NF, rawb, Abf,
             X, nullptr, nullptr, nullptr, 0);
  // XV = X @ V^T
  launch_bt2(std::integral_constant<int, EPI_BF16>{}, T_STEPS * BB, NH, NI, X, Vm,
             XV, nullptr, nullptr, nullptr, 0);

  // Entire scan (16 t-steps x 5 prox iterations) in ONE persistent kernel.
  scan_persist<<<dim3(256), 256, 0, stream>>>(
      H0, W1m, Sm, Gt, XV, Hb0, Hb1, HS, alp, l0, l1, cnt);

  // z_hat = HS @ D^T (fp32 direct to d_out)
  launch_bt2(std::integral_constant<int, EPI_F32>{}, T_STEPS * BB, NF, NH, HS, Dbf,
             nullptr, outp, nullptr, nullptr, 0);
}

// Round 6
// 1441.340 us; speedup vs baseline: 2.5958x; 2.5958x over previous
//
#include <hip/hip_runtime.h>
#include <cstdint>
#include <cstddef>
#include <type_traits>

#define T_STEPS 16
#define BB 512
#define NF 1024
#define NI 256
#define NH 2048
#define KSTEPS 5

typedef __bf16 bf16;
typedef __bf16 bf16x8 __attribute__((ext_vector_type(8)));
typedef __bf16 bf16x4 __attribute__((ext_vector_type(4)));
typedef float f32x4 __attribute__((ext_vector_type(4)));

enum { EPI_BF16 = 0, EPI_F32 = 1, EPI_TEMPS = 2, EPI_W1 = 3 };

__device__ __forceinline__ void gload_lds16(const bf16* g, void* l) {
  __builtin_amdgcn_global_load_lds(
      (const __attribute__((address_space(1))) void*)g,
      (__attribute__((address_space(3))) void*)l, 16, 0, 0);
}
// system-scope (sc0|sc1 = 1|16): forced L2 miss -> reads fresh data from MALL
__device__ __forceinline__ void gload_lds16_sys(const bf16* g, void* l) {
  __builtin_amdgcn_global_load_lds(
      (const __attribute__((address_space(1))) void*)g,
      (__attribute__((address_space(3))) void*)l, 16, 0, 17);
}
// write-through system-scope store: visible at coherence point after vmcnt(0)
__device__ __forceinline__ void store_bf16_sys(bf16* p, float v) {
  unsigned int u = (unsigned int)__builtin_bit_cast(unsigned short, (bf16)v);
  asm volatile("global_store_short %0, %1, off sc0 sc1" :: "v"(p), "v"(u) : "memory");
}

// faithful multi-branch prox of w0*|x| + w1*|x - a1|
__device__ __forceinline__ float soft_l1_l1(float z, float w0, float w1, float a1) {
  bool c = (0.0f <= a1);
  float a0s = c ? 0.0f : a1;
  float a1s = c ? a1 : 0.0f;
  float w0s = c ? w0 : w1;
  float w1s = c ? w1 : w0;
  if (z >= a1s + w0s + w1s) return z - w0s - w1s;
  if (z >= a1s + w0s - w1s) return a1s;
  if (z >= a0s + w0s - w1s) return z - w0s + w1s;
  if (z >= a0s - w0s - w1s) return a0s;
  return z + w0s + w1s;
}

// ---------------------------------------------------------------------------
// Batched GEMM (unchanged from round 5): 128x128 tile, BK=64, D=2 buffers,
// counted vmcnt(8) + raw barriers, XCD chunking with col-fastest decode.
// ---------------------------------------------------------------------------
template<int EPI>
__global__ __launch_bounds__(256)
void gemm_bt2(const bf16* __restrict__ Ag, const bf16* __restrict__ Bg,
              int N, int Kd, int nby, int total,
              bf16* __restrict__ outb, float* __restrict__ outf,
              bf16* __restrict__ out2, const float* __restrict__ srcf,
              const float* __restrict__ alpha, int inv_alpha)
{
  __shared__ char smem[65536];
  const int tid = threadIdx.x, lane = tid & 63, wid = tid >> 6;
  const int wr = wid >> 1, wc = wid & 1;
  const int r16 = lane & 15, q16 = lane >> 4;
  const int bid = blockIdx.x;
  const int wg = (bid & 7) * (total >> 3) + (bid >> 3);
  const int bm0 = (wg / nby) * 128, bn0 = (wg % nby) * 128;
  const int sw = r16 & 7;

  f32x4 acc[4][4] = {};

  auto stage = [&](int buf, int kt) {
    char* da = smem + buf * 32768;
    char* db = da + 16384;
#pragma unroll
    for (int it = 0; it < 4; ++it) {
      int idx = it * 256 + tid;
      int row = idx >> 3, sc = (idx & 7) ^ (row & 7);
      gload_lds16(Ag + (size_t)(bm0 + row) * Kd + kt + sc * 8, da + idx * 16);
    }
#pragma unroll
    for (int it = 0; it < 4; ++it) {
      int idx = it * 256 + tid;
      int row = idx >> 3, sc = (idx & 7) ^ (row & 7);
      gload_lds16(Bg + (size_t)(bn0 + row) * Kd + kt + sc * 8, db + idx * 16);
    }
  };

  auto compute = [&](int buf) {
    const char* Ab = smem + buf * 32768;
    const char* Bb = Ab + 16384;
#pragma unroll
    for (int kk = 0; kk < 2; ++kk) {
      int ch = ((kk * 4 + q16) ^ sw) * 16;
      bf16x8 af[4], bfr[4];
#pragma unroll
      for (int i = 0; i < 4; ++i)
        af[i] = *(const bf16x8*)(Ab + (wr * 64 + i * 16 + r16) * 128 + ch);
#pragma unroll
      for (int j = 0; j < 4; ++j)
        bfr[j] = *(const bf16x8*)(Bb + (wc * 64 + j * 16 + r16) * 128 + ch);
#pragma unroll
      for (int i = 0; i < 4; ++i)
#pragma unroll
        for (int j = 0; j < 4; ++j)
          acc[i][j] = __builtin_amdgcn_mfma_f32_16x16x32_bf16(af[i], bfr[j], acc[i][j], 0, 0, 0);
    }
  };

  const int NT = Kd >> 6;
  stage(0, 0);
  int t = 0;
  for (; t < NT - 1; ++t) {
    stage((t + 1) & 1, (t + 1) * 64);
    asm volatile("s_waitcnt vmcnt(8)" ::: "memory");
    __builtin_amdgcn_s_barrier();
    __builtin_amdgcn_sched_barrier(0);
    compute(t & 1);
    __builtin_amdgcn_sched_barrier(0);
    __builtin_amdgcn_s_barrier();
  }
  asm volatile("s_waitcnt vmcnt(0)" ::: "memory");
  __builtin_amdgcn_s_barrier();
  __builtin_amdgcn_sched_barrier(0);
  compute(t & 1);

  float scale = inv_alpha ? 1.f / alpha[0] : 1.f;
#pragma unroll
  for (int i = 0; i < 4; ++i) {
#pragma unroll
    for (int j = 0; j < 4; ++j) {
#pragma unroll
      for (int e = 0; e < 4; ++e) {
        int m = bm0 + wr * 64 + i * 16 + q16 * 4 + e;
        int n = bn0 + wc * 64 + j * 16 + r16;
        size_t o = (size_t)m * N + n;
        float v = acc[i][j][e] * scale;
        if (EPI == EPI_BF16) {
          outb[o] = (bf16)v;
        } else if (EPI == EPI_F32) {
          outf[o] = v;
        } else if (EPI == EPI_TEMPS) {
          outb[o] = (bf16)v;
          out2[o] = (bf16)((m == n ? 1.f : 0.f) - v);
        } else { // EPI_W1
          outb[o] = (bf16)(srcf[o] - v);
        }
      }
    }
  }
}

// ---------------------------------------------------------------------------
// Persistent scan v2. 256 blocks (1/CU) x 256 thr. Tile 32 rows x 128 cols
// per block (16 row-tiles x 16 col-tiles); each wave owns 32x32 over FULL
// K=2048 -> NO cross-wave reduce. Weights (S/W1/G slices, 3MB/XCD) are read
// with NORMAL loads -> stay L2-resident across all 80 phases (no fences!).
// h is the only cross-XCD-coherent data: stores write-through (sc0 sc1),
// staging loads force-miss L2 (aux=17). Grid barrier: relaxed atomics,
// hierarchical (8 per-XCD counters + master), NO __threadfence.
// Next phase's first weight tile is prefetched under the barrier.
// ---------------------------------------------------------------------------
template<bool DUAL>
__device__ __forceinline__ void stage_w(char* smem, const bf16* B1, const bf16* B2,
                                        int bn0, int tid) {
  char* base = smem + 8192;   // buffer 0, B1 area
#pragma unroll
  for (int it = 0; it < 8; ++it) {
    int idx = it * 256 + tid;
    int row = idx >> 4, sc = (idx & 15) ^ (row & 7);
    gload_lds16(B1 + (size_t)(bn0 + row) * NH + sc * 8, base + idx * 16);
  }
  if constexpr (DUAL) {
    char* g = smem + 40960;
#pragma unroll
    for (int it = 0; it < 8; ++it) {
      int idx = it * 256 + tid;
      int row = idx >> 4, sc = (idx & 15) ^ (row & 7);
      gload_lds16(B2 + (size_t)(bn0 + row) * NH + sc * 8, g + idx * 16);
    }
  }
}

template<bool DUAL>
__device__ __forceinline__ void phase_gemm(char* smem, const bf16* hp,
    const bf16* B1, const bf16* B2, int bm0, int bn0, int tid,
    f32x4 (&acc)[2][2], f32x4 (&accG)[2][2])
{
  const int lane = tid & 63, wid = tid >> 6;
  const int r16 = lane & 15, q16 = lane >> 4;
  const int sw = r16 & 7;
  constexpr int BSTR = 73728;   // per-buffer: A 8K @0, B1 32K @8192, B2 32K @40960

#pragma unroll
  for (int i = 0; i < 2; ++i)
#pragma unroll
    for (int j = 0; j < 2; ++j) {
      acc[i][j] = f32x4{0.f, 0.f, 0.f, 0.f};
      if constexpr (DUAL) accG[i][j] = f32x4{0.f, 0.f, 0.f, 0.f};
    }

  auto stageA = [&](int buf, int kt) {
    char* base = smem + buf * BSTR;
#pragma unroll
    for (int it = 0; it < 2; ++it) {
      int idx = it * 256 + tid;
      int row = idx >> 4, sc = (idx & 15) ^ (row & 7);
      gload_lds16_sys(hp + (size_t)(bm0 + row) * NH + kt + sc * 8, base + idx * 16);
    }
  };
  auto stageB = [&](int buf, int kt) {
    char* base = smem + buf * BSTR + 8192;
#pragma unroll
    for (int it = 0; it < 8; ++it) {
      int idx = it * 256 + tid;
      int row = idx >> 4, sc = (idx & 15) ^ (row & 7);
      gload_lds16(B1 + (size_t)(bn0 + row) * NH + kt + sc * 8, base + idx * 16);
    }
    if constexpr (DUAL) {
      char* g = smem + buf * BSTR + 40960;
#pragma unroll
      for (int it = 0; it < 8; ++it) {
        int idx = it * 256 + tid;
        int row = idx >> 4, sc = (idx & 15) ^ (row & 7);
        gload_lds16(B2 + (size_t)(bn0 + row) * NH + kt + sc * 8, g + idx * 16);
      }
    }
  };
  auto compute = [&](int buf) {
    const char* Ab = smem + buf * BSTR;
    const char* Bb = Ab + 8192;
    const char* Gb = Ab + 40960;
#pragma unroll
    for (int kk = 0; kk < 4; ++kk) {
      const int ch = ((kk * 4 + q16) ^ sw) * 16;
      bf16x8 af[2], bf_[2];
#pragma unroll
      for (int i = 0; i < 2; ++i)
        af[i] = *(const bf16x8*)(Ab + (i * 16 + r16) * 256 + ch);
#pragma unroll
      for (int j = 0; j < 2; ++j)
        bf_[j] = *(const bf16x8*)(Bb + (wid * 32 + j * 16 + r16) * 256 + ch);
#pragma unroll
      for (int i = 0; i < 2; ++i)
#pragma unroll
        for (int j = 0; j < 2; ++j)
          acc[i][j] = __builtin_amdgcn_mfma_f32_16x16x32_bf16(af[i], bf_[j], acc[i][j], 0, 0, 0);
      if constexpr (DUAL) {
        bf16x8 bg[2];
#pragma unroll
        for (int j = 0; j < 2; ++j)
          bg[j] = *(const bf16x8*)(Gb + (wid * 32 + j * 16 + r16) * 256 + ch);
#pragma unroll
        for (int i = 0; i < 2; ++i)
#pragma unroll
          for (int j = 0; j < 2; ++j)
            accG[i][j] = __builtin_amdgcn_mfma_f32_16x16x32_bf16(af[i], bg[j], accG[i][j], 0, 0, 0);
      }
    }
  };

  stageA(0, 0);   // B-tile 0 was prefetched under the previous grid barrier
#pragma unroll 1
  for (int tt = 0; tt < 16; ++tt) {
    if (tt < 15) {
      int nb = (tt + 1) & 1, kt = (tt + 1) * 128;
      stageA(nb, kt);
      stageB(nb, kt);
      // wait = exactly the next-tile load count; older stray ops drain too (safe)
      if constexpr (DUAL) asm volatile("s_waitcnt vmcnt(18)" ::: "memory");
      else                asm volatile("s_waitcnt vmcnt(10)" ::: "memory");
    } else {
      asm volatile("s_waitcnt vmcnt(0)" ::: "memory");
    }
    __builtin_amdgcn_s_barrier();
    __builtin_amdgcn_sched_barrier(0);
    compute(tt & 1);
    __builtin_amdgcn_sched_barrier(0);
    __builtin_amdgcn_s_barrier();
  }
}

__global__ __launch_bounds__(256, 1)
void scan_persist(const bf16* __restrict__ H0, const bf16* __restrict__ W1m,
                  const bf16* __restrict__ Sm, const bf16* __restrict__ Gt,
                  const bf16* __restrict__ XV, bf16* __restrict__ Hb0,
                  bf16* __restrict__ Hb1, bf16* __restrict__ HS,
                  const float* __restrict__ alpha, const float* __restrict__ lam0,
                  const float* __restrict__ lam1, unsigned* __restrict__ cnt)
{
  __shared__ char smem[147456];
  const int tid = threadIdx.x, lane = tid & 63, wid = tid >> 6;
  const int r16 = lane & 15, q16 = lane >> 4;
  const int bid = blockIdx.x;
  const int xcd = bid & 7, r = bid >> 3;
  const int bn0 = (xcd * 2 + (r & 1)) * 128;   // XCD x owns cols [x*256, x*256+256)
  const int bm0 = (r >> 1) * 32;               // 16 row-tiles of 32

  const float al = alpha[0];
  const float w0 = lam0[0] / al, w1 = lam1[0] / al;
  const size_t HBsz = (size_t)BB * NH;

  unsigned* cnt8 = cnt;          // 8 slots @ stride 32 u32 (128B apart)
  unsigned* master = cnt + 256;

  unsigned bar_no = 0;
  f32x4 acc[2][2], accG[2][2];
  float xvreg[16], a1reg[16];

  stage_w<true>(smem, W1m, Gt, bn0, tid);   // prefetch first phase's weights

#pragma unroll 1
  for (int p = 0; p < T_STEPS * KSTEPS; ++p) {
    const int t = p / KSTEPS, k = p % KSTEPS;
    const bf16* hp;
    bf16* dst;
    if (k == 0) {
      hp = (t == 0) ? H0 : HS + (size_t)(t - 1) * HBsz;
      dst = Hb0;
    } else {
      hp = (k & 1) ? Hb0 : Hb1;
      dst = (k == KSTEPS - 1) ? HS + (size_t)t * HBsz : ((k & 1) ? Hb1 : Hb0);
    }

    if (k == 0) {
      const bf16* xvt = XV + (size_t)t * HBsz;
#pragma unroll
      for (int i = 0; i < 2; ++i)
#pragma unroll
        for (int j = 0; j < 2; ++j)
#pragma unroll
          for (int e = 0; e < 4; ++e)
            xvreg[(i * 2 + j) * 4 + e] =
                (float)xvt[(size_t)(bm0 + i * 16 + q16 * 4 + e) * NH
                           + bn0 + wid * 32 + j * 16 + r16];
      phase_gemm<true>(smem, hp, W1m, Gt, bm0, bn0, tid, acc, accG);
#pragma unroll
      for (int i = 0; i < 2; ++i)
#pragma unroll
        for (int j = 0; j < 2; ++j)
#pragma unroll
          for (int e = 0; e < 4; ++e)
            a1reg[(i * 2 + j) * 4 + e] = accG[i][j][e];
    } else {
      phase_gemm<false>(smem, hp, Sm, nullptr, bm0, bn0, tid, acc, accG);
    }

    // epilogue: shrink + write-through store (cross-XCD visible after vmcnt(0))
#pragma unroll
    for (int i = 0; i < 2; ++i)
#pragma unroll
      for (int j = 0; j < 2; ++j)
#pragma unroll
        for (int e = 0; e < 4; ++e) {
          float z = acc[i][j][e] + xvreg[(i * 2 + j) * 4 + e];
          float h = soft_l1_l1(z, w0, w1, a1reg[(i * 2 + j) * 4 + e]);
          store_bf16_sys(dst + (size_t)(bm0 + i * 16 + q16 * 4 + e) * NH
                             + bn0 + wid * 32 + j * 16 + r16, h);
        }

    asm volatile("s_waitcnt vmcnt(0)" ::: "memory");   // release: h in MALL
    __builtin_amdgcn_sched_barrier(0);
    if (p + 1 < T_STEPS * KSTEPS) {       // prefetch next weights under barrier
      if ((p + 1) % KSTEPS == 0) stage_w<true>(smem, W1m, Gt, bn0, tid);
      else                       stage_w<false>(smem, Sm, nullptr, bn0, tid);
    }
    __builtin_amdgcn_s_barrier();
    ++bar_no;
    if (tid == 0) {
      __hip_atomic_fetch_add(&cnt8[xcd * 32], 1u, __ATOMIC_RELAXED, __HIP_MEMORY_SCOPE_AGENT);
      if (r == 0) {   // XCD leader aggregates
        while (__hip_atomic_load(&cnt8[xcd * 32], __ATOMIC_RELAXED, __HIP_MEMORY_SCOPE_AGENT)
               < 32u * bar_no)
          __builtin_amdgcn_s_sleep(1);
        __hip_atomic_fetch_add(master, 1u, __ATOMIC_RELAXED, __HIP_MEMORY_SCOPE_AGENT);
      }
      while (__hip_atomic_load(master, __ATOMIC_RELAXED, __HIP_MEMORY_SCOPE_AGENT)
             < 8u * bar_no)
        __builtin_amdgcn_s_sleep(1);
    }
    __builtin_amdgcn_s_barrier();
    __builtin_amdgcn_sched_barrier(0);
  }
}

__global__ void zero_u32s(unsigned* p, int n) {
  int i = blockIdx.x * 256 + threadIdx.x;
  if (i < n) p[i] = 0;
}

__global__ void cast_f32_bf16(const float* __restrict__ in, bf16* __restrict__ out, int n) {
  int i = (blockIdx.x * blockDim.x + threadIdx.x) * 4;
  if (i + 4 <= n) {
    float4 v = *(const float4*)&in[i];
    bf16x4 p;
    p[0] = (bf16)v.x; p[1] = (bf16)v.y; p[2] = (bf16)v.z; p[3] = (bf16)v.w;
    *(bf16x4*)&out[i] = p;
  } else {
    for (; i < n; ++i) out[i] = (bf16)in[i];
  }
}

// out[c,r] = (bf16) in[r,c];  in: [R,C] f32 row-major -> out: [C,R] bf16 row-major
__global__ void transpose_cast(const float* __restrict__ in, bf16* __restrict__ out, int R, int C) {
  __shared__ float tile[32][33];
  int bx = blockIdx.x * 32, by = blockIdx.y * 32;
  int tx = threadIdx.x, ty = threadIdx.y;
  for (int i = ty; i < 32; i += 8) {
    int r = by + i, c = bx + tx;
    if (r < R && c < C) tile[i][tx] = in[(size_t)r * C + c];
  }
  __syncthreads();
  for (int i = ty; i < 32; i += 8) {
    int r = bx + i, c = by + tx;
    if (r < C && c < R) out[(size_t)r * R + c] = (bf16)tile[tx][i];
  }
}

extern "C" void kernel_launch(void* const* d_in, const int* in_sizes, int n_in,
                              void* d_out, int out_size, void* d_ws, size_t ws_size,
                              hipStream_t stream) {
  // inputs: 0 pre_input (unused), 1 raw, 2 A, 3 D, 4 G, 5 h_0,
  //         6 alpha, 7 lambda0, 8 lambda1, 9 K (fixed = 5)
  const float* rawf = (const float*)d_in[1];
  const float* Af   = (const float*)d_in[2];
  const float* Df   = (const float*)d_in[3];
  const float* Gf   = (const float*)d_in[4];
  const float* h0f  = (const float*)d_in[5];
  const float* alp  = (const float*)d_in[6];
  const float* l0   = (const float*)d_in[7];
  const float* l1   = (const float*)d_in[8];
  float* outp = (float*)d_out;

  char* w = (char*)d_ws;
  auto allocb = [&](size_t bytes) { char* p = w; w += (bytes + 255) & ~(size_t)255; return p; };
  bf16* Abf  = (bf16*)allocb((size_t)NI * NF * 2);
  bf16* At   = (bf16*)allocb((size_t)NF * NI * 2);
  bf16* Dbf  = (bf16*)allocb((size_t)NF * NH * 2);
  bf16* Dt   = (bf16*)allocb((size_t)NH * NF * 2);
  bf16* Gt   = (bf16*)allocb((size_t)NH * NH * 2);
  bf16* rawb = (bf16*)allocb((size_t)T_STEPS * BB * NF * 2);
  bf16* AtA  = (bf16*)allocb((size_t)NF * NF * 2);
  bf16* Vm   = (bf16*)allocb((size_t)NH * NI * 2);
  bf16* M3t  = (bf16*)allocb((size_t)NH * NF * 2);
  bf16* tmpb = (bf16*)allocb((size_t)NH * NH * 2);
  bf16* Sm   = (bf16*)allocb((size_t)NH * NH * 2);
  bf16* W1m  = (bf16*)allocb((size_t)NH * NH * 2);
  bf16* X    = (bf16*)allocb((size_t)T_STEPS * BB * NI * 2);
  bf16* H0   = (bf16*)allocb((size_t)BB * NH * 2);
  bf16* Hb0  = (bf16*)allocb((size_t)BB * NH * 2);
  bf16* Hb1  = (bf16*)allocb((size_t)BB * NH * 2);
  bf16* HS   = (bf16*)allocb((size_t)T_STEPS * BB * NH * 2);
  unsigned* cnt = (unsigned*)allocb(4096);
  // XV (T*B x NH bf16 = 33.5 MB) lives in d_out: fully written before use, dead
  // before the final projection overwrites d_out.
  bf16* XV   = (bf16*)d_out;

  zero_u32s<<<dim3(2), 256, 0, stream>>>(cnt, 512);

  auto cgrid = [](int n) { return dim3((unsigned)((n / 4 + 255) / 256)); };
  cast_f32_bf16<<<cgrid(NI * NF), 256, 0, stream>>>(Af, Abf, NI * NF);
  cast_f32_bf16<<<cgrid(NF * NH), 256, 0, stream>>>(Df, Dbf, NF * NH);
  cast_f32_bf16<<<cgrid(T_STEPS * BB * NF), 256, 0, stream>>>(rawf, rawb, T_STEPS * BB * NF);
  cast_f32_bf16<<<cgrid(BB * NH), 256, 0, stream>>>(h0f, H0, BB * NH);
  transpose_cast<<<dim3(NF / 32, NI / 32), dim3(32, 8), 0, stream>>>(Af, At, NI, NF);
  transpose_cast<<<dim3(NH / 32, NF / 32), dim3(32, 8), 0, stream>>>(Df, Dt, NF, NH);
  transpose_cast<<<dim3(NH / 32, NH / 32), dim3(32, 8), 0, stream>>>(Gf, Gt, NH, NH);

  auto launch_bt2 = [&](auto epi_tag, int Mrows, int Ncols, int Kd,
                        const bf16* Ap, const bf16* Bp,
                        bf16* ob, float* of, bf16* o2, const float* sf, int inva) {
    constexpr int EPIv = decltype(epi_tag)::value;
    int nbx = Mrows / 128, nby = Ncols / 128, total = nbx * nby;
    gemm_bt2<EPIv><<<dim3(total), 256, 0, stream>>>(
        Ap, Bp, Ncols, Kd, nby, total, ob, of, o2, sf, alp, inva);
  };

  // AtA[f1,f2] = sum_i A[i,f1]A[i,f2]
  launch_bt2(std::integral_constant<int, EPI_BF16>{}, NF, NF, NI, At, At,
             AtA, nullptr, nullptr, nullptr, 0);
  // V[h,i] = (1/al) sum_f D[f,h]A[i,f]
  launch_bt2(std::integral_constant<int, EPI_BF16>{}, NH, NI, NF, Dt, Abf,
             Vm, nullptr, nullptr, nullptr, 1);
  // M3t[h,f] = sum_f2 Dt[h,f2]AtA[f,f2] = (AtA@D)[f,h]  (AtA symmetric)
  launch_bt2(std::integral_constant<int, EPI_BF16>{}, NH, NF, NF, Dt, AtA,
             M3t, nullptr, nullptr, nullptr, 0);
  // temp = (1/al) D^T (AtA D); S = I - temp (dual store)
  launch_bt2(std::integral_constant<int, EPI_TEMPS>{}, NH, NH, NF, Dt, M3t,
             tmpb, nullptr, Sm, nullptr, 1);
  // W1 = G - temp@G
  launch_bt2(std::integral_constant<int, EPI_W1>{}, NH, NH, NH, tmpb, Gt,
             W1m, nullptr, nullptr, Gf, 0);
  // X = raw @ A^T
  launch_bt2(std::integral_constant<int, EPI_BF16>{}, T_STEPS * BB, NI, NF, rawb, Abf,
             X, nullptr, nullptr, nullptr, 0);
  // XV = X @ V^T
  launch_bt2(std::integral_constant<int, EPI_BF16>{}, T_STEPS * BB, NH, NI, X, Vm,
             XV, nullptr, nullptr, nullptr, 0);

  // Entire scan (16 t-steps x 5 prox iterations) in ONE persistent kernel.
  scan_persist<<<dim3(256), 256, 0, stream>>>(
      H0, W1m, Sm, Gt, XV, Hb0, Hb1, HS, alp, l0, l1, cnt);

  // z_hat = HS @ D^T (fp32 direct to d_out)
  launch_bt2(std::integral_constant<int, EPI_F32>{}, T_STEPS * BB, NF, NH, HS, Dbf,
             nullptr, outp, nullptr, nullptr, 0);
}